// Round 15
// baseline (67.354 us; speedup 1.0000x reference)
//
#include <hip/hip_runtime.h>
#include <math.h>

namespace {
constexpr int kB = 32;
constexpr int kN = 100000;
constexpr int kL = 12;
constexpr int kS = 256;
constexpr int kBG = 8;                      // poses per block in deform kernel
constexpr int kWOwn = 62;                   // atoms OWNED per wave (2 shuffle-halo lanes)
constexpr int kTile = 4 * kWOwn;            // 248 atoms owned per 256-thread block
constexpr int kNB = (kN + kTile - 1) / kTile;  // 404 atom-blocks
constexpr int kSlot = 64;                   // slots per (pose, band, source-block)
constexpr int kKx = 130;                    // stored kx columns (129 used + pad)

constexpr float kGauss = (float)(2.0 * M_PI * M_PI);                         // 2(pi*sigma)^2, sigma=1
constexpr float kA1 = (float)(M_PI * 0.0197);                                // pi*lambda
constexpr float kA2 = (float)(0.5 * M_PI * 2.7e7 * 0.0197 * 0.0197 * 0.0197);// 0.5*pi*Cs*lambda^3
constexpr float kW1 = 0.99498743710661995f;                                  // sqrt(1-Q0^2)
constexpr float kQ0 = 0.1f;
}

__device__ __forceinline__ void build_tw(float2* tw, int t) {
  if (t < 128) {
    float s, c;
    sincosf((float)M_PI / 128.0f * (float)t, &s, &c);
    tw[t] = make_float2(c, s);
  }
}

// ---------------------------------------------------------------------------
// PER-WAVE 256-point Stockham radix-4 FFT: 64 lanes, 4 float2 regs/lane,
// 4 stages (m = 1,4,16,64), single 256-float2 LDS work buffer, NO barriers.
// ---------------------------------------------------------------------------
template <int SIGN>
__device__ __forceinline__ void fft256w(float2 v[4], float2* fb, int lane,
                                        const float2* tw) {
#pragma unroll
  for (int m = 1; m <= 64; m *= 4) {
    int l = lane & (m - 1);
    int jm = lane - l;                 // u*m
    float2 wv = tw[jm];
    float c = wv.x;
    float s = (SIGN < 0) ? -wv.y : wv.y;
    float2 A0 = v[0], A1 = v[1], A2 = v[2], A3 = v[3];
    float s02x = A0.x + A2.x, s02y = A0.y + A2.y;
    float d02x = A0.x - A2.x, d02y = A0.y - A2.y;
    float s13x = A1.x + A3.x, s13y = A1.y + A3.y;
    float d13x = A1.x - A3.x, d13y = A1.y - A3.y;
    float jdx = (SIGN < 0) ? d13y : -d13y;      // sgn*i*(d13)
    float jdy = (SIGN < 0) ? -d13x : d13x;
    float t1x = d02x + jdx, t1y = d02y + jdy;
    float t2x = s02x - s13x, t2y = s02y - s13y;
    float t3x = d02x - jdx, t3y = d02y - jdy;
    float c2 = c * c - s * s, s2 = 2.f * c * s;
    float c3 = c2 * c - s2 * s, s3 = c2 * s + s2 * c;
    int ob = 4 * jm + l;
    fb[ob]         = make_float2(s02x + s13x, s02y + s13y);
    fb[ob + m]     = make_float2(c * t1x - s * t1y, c * t1y + s * t1x);
    fb[ob + 2 * m] = make_float2(c2 * t2x - s2 * t2y, c2 * t2y + s2 * t2x);
    fb[ob + 3 * m] = make_float2(c3 * t3x - s3 * t3y, c3 * t3y + s3 * t3x);
    v[0] = fb[lane];
    v[1] = fb[lane + 64];
    v[2] = fb[lane + 128];
    v[3] = fb[lane + 192];
  }
}

// ---------------------------------------------------------------------------
// Phase A: deformation -> bond, angle, projected (x,y) packed u16.8 scattered
// DIRECTLY into deterministic per-(pose, band, source-block) 64-slot chunks.
// 1D grid with XCD-aware remap: all 4 pose-group clones of the same atom
// block xb get linear ids congruent mod 8 -> same XCD -> basis L2 reuse.
// ---------------------------------------------------------------------------
__global__ __launch_bounds__(256) void k_deform(
    const float* __restrict__ c_nma, const float* __restrict__ delta_euler,
    const float* __restrict__ delta_shifts, const float* __restrict__ coords,
    const float* __restrict__ basis_x, const float* __restrict__ basis_y,
    const float* __restrict__ basis_z, const float* __restrict__ euler_base,
    const float* __restrict__ shifts_base,
    unsigned* __restrict__ xy_bkt, int* __restrict__ cnt,
    float* __restrict__ bond, float* __restrict__ angle) {
  __shared__ float cn_s[kBG][kL];
  __shared__ float rsh_s[kBG][8];
  __shared__ int bcnt[kBG][8];

  const int t = threadIdx.x;
  const int wave = t >> 6, lane = t & 63;
  // remap: ids < 1600 -> xcd = id%8, grp = id/8; yg = grp%4, xb = xcd + 8*(grp/4)
  const int id = blockIdx.x;
  int xb, yg;
  if (id < 1600) {
    int xcd = id & 7, grp = id >> 3;
    yg = grp & 3;
    xb = xcd + 8 * (grp >> 2);            // 0..399
  } else {
    int r = id - 1600;                    // 0..15
    xb = 400 + (r >> 2);                  // 400..403
    yg = r & 3;
  }
  const int bg = yg * kBG;
  const int n = xb * kTile + wave * kWOwn + lane;
  const bool owner = (lane < kWOwn) && (n < kN);
  const int nc = min(n, kN - 1);

  if (t < kBG * kL) cn_s[t / kL][t % kL] = c_nma[(bg + t / kL) * kL + (t % kL)];
  if (t < kBG) {
    int b = bg + t;
    float rot  = euler_base[b * 3 + 0] + delta_euler[b * 3 + 0];
    float tilt = euler_base[b * 3 + 1] + delta_euler[b * 3 + 1];
    float psi  = euler_base[b * 3 + 2] + delta_euler[b * 3 + 2];
    float ca = cosf(rot), sa = sinf(rot);
    float cb = cosf(tilt), sb = sinf(tilt);
    float cg = cosf(psi), sg = sinf(psi);
    rsh_s[t][0] = cg * cb * ca - sg * sa;
    rsh_s[t][1] = cg * cb * sa + sg * ca;
    rsh_s[t][2] = -cg * sb;
    rsh_s[t][3] = -sg * cb * ca - cg * sa;
    rsh_s[t][4] = -sg * cb * sa + cg * ca;
    rsh_s[t][5] = sg * sb;
    rsh_s[t][6] = shifts_base[b * 2 + 0] + delta_shifts[b * 2 + 0] + 128.0f;
    rsh_s[t][7] = shifts_base[b * 2 + 1] + delta_shifts[b * 2 + 1] + 128.0f;
  }
  if (t < kBG * 8) bcnt[t >> 3][t & 7] = 0;

  const float cx = coords[nc * 3 + 0];
  const float cy = coords[nc * 3 + 1];
  const float cz = coords[nc * 3 + 2];
  float bx[kL], by[kL], bz[kL];
  {
    const float4* px4 = reinterpret_cast<const float4*>(basis_x + (size_t)nc * kL);
    const float4* py4 = reinterpret_cast<const float4*>(basis_y + (size_t)nc * kL);
    const float4* pz4 = reinterpret_cast<const float4*>(basis_z + (size_t)nc * kL);
#pragma unroll
    for (int q = 0; q < 3; ++q) {
      float4 vx = px4[q], vy = py4[q], vz = pz4[q];
      bx[q * 4 + 0] = vx.x; bx[q * 4 + 1] = vx.y; bx[q * 4 + 2] = vx.z; bx[q * 4 + 3] = vx.w;
      by[q * 4 + 0] = vy.x; by[q * 4 + 1] = vy.y; by[q * 4 + 2] = vy.z; by[q * 4 + 3] = vy.w;
      bz[q * 4 + 0] = vz.x; bz[q * 4 + 1] = vz.y; bz[q * 4 + 2] = vz.z; bz[q * 4 + 3] = vz.w;
    }
  }
  __syncthreads();

#pragma unroll
  for (int bi = 0; bi < kBG; ++bi) {
    const int b = bg + bi;
    float px = cx, py = cy, pz = cz;
#pragma unroll
    for (int l = 0; l < kL; ++l) {
      float cc = cn_s[bi][l];
      px = fmaf(cc, bx[l], px);
      py = fmaf(cc, by[l], py);
      pz = fmaf(cc, bz[l], pz);
    }
    float p1x = __shfl_down(px, 1), p1y = __shfl_down(py, 1), p1z = __shfl_down(pz, 1);
    float dx = p1x - px, dy = p1y - py, dz = p1z - pz;
    float dd = fmaf(dx, dx, fmaf(dy, dy, dz * dz));
    float d1x = __shfl_down(dx, 1), d1y = __shfl_down(dy, 1), d1z = __shfl_down(dz, 1);

    if (owner) {
      float xr = fmaf(rsh_s[bi][0], px, fmaf(rsh_s[bi][1], py, fmaf(rsh_s[bi][2], pz, rsh_s[bi][6])));
      float yr = fmaf(rsh_s[bi][3], px, fmaf(rsh_s[bi][4], py, fmaf(rsh_s[bi][5], pz, rsh_s[bi][7])));
      xr = fminf(fmaxf(xr, 0.0f), 254.999f);
      yr = fminf(fmaxf(yr, 0.0f), 254.999f);
      unsigned xf = (unsigned)(xr * 256.0f);   // <= 65279 -> x0 <= 254
      unsigned yf = (unsigned)(yr * 256.0f);
      unsigned u = (yf << 16) | xf;
      unsigned y0i = yf >> 8;                  // 0..254
      unsigned band = y0i >> 5;                // 0..7
      int rank = atomicAdd(&bcnt[bi][band], 1);
      if (rank < kSlot)
        __builtin_nontemporal_store(
            u, &xy_bkt[(((size_t)b * 8 + band) * kNB + xb) * kSlot + rank]);
      if ((y0i & 31u) == 31u) {                // footprint straddles band edge
        unsigned band1 = band + 1;             // y0i<=223 -> band1<=7
        int r2 = atomicAdd(&bcnt[bi][band1], 1);
        if (r2 < kSlot)
          __builtin_nontemporal_store(
              u, &xy_bkt[(((size_t)b * 8 + band1) * kNB + xb) * kSlot + r2]);
      }
      if (n < kN - 1) {
        __builtin_nontemporal_store(sqrtf(dd + 1e-12f),
                                    &bond[(size_t)b * (kN - 1) + n]);
      }
      if (n < kN - 2) {
        float vv = fmaf(d1x, d1x, fmaf(d1y, d1y, d1z * d1z));
        float uv = -fmaf(dx, d1x, fmaf(dy, d1y, dz * d1z));
        float cosang = uv * rsqrtf(dd * vv);
        cosang = fminf(fmaxf(cosang, -0.9999f), 0.9999f);
        float ax = fabsf(cosang);
        float rt = sqrtf(1.0f - ax);
        float pp = fmaf(fmaf(fmaf(-0.0187293f, ax, 0.0742610f), ax, -0.2121144f),
                        ax, 1.5707288f);
        float res = rt * pp;
        __builtin_nontemporal_store((cosang >= 0.f) ? res : (float)M_PI - res,
                                    &angle[(size_t)b * (kN - 2) + n]);
      }
    }
  }
  __syncthreads();
  if (t < kBG * 8) {
    int po = t >> 3, bandx = t & 7;
    cnt[((bg + po) * 8 + bandx) * kNB + xb] = min(bcnt[po][bandx], kSlot);
  }
}

// ---------------------------------------------------------------------------
// Phase B (FUSED): splat from per-(pose,band) chunked slot lists into a
// 32x256 u18.14 LDS tile + 16 per-wave packed real row-FFTs, writing the
// Hermitian-reduced transposed spectrum FcT[b][kx][y] directly.
// grid: 32 poses * 8 bands, 1024 threads. Slot loads are predicated on the
// chunk count (unfilled slots are never fetched).
// ---------------------------------------------------------------------------
__global__ __launch_bounds__(1024) void k_splat_fft(
    const unsigned* __restrict__ xy_bkt, const int* __restrict__ cnt,
    float2* __restrict__ FcT) {
  __shared__ unsigned tile[32 * 256];
  __shared__ float2 fbuf[16][256];
  __shared__ float2 tw[128];
  __shared__ int cnt_s[kNB];
  const int t = threadIdx.x;
  const int b = blockIdx.x >> 3;
  const int band = blockIdx.x & 7;
  const int r0 = band * 32;
  build_tw(tw, t);
  for (int i = t; i < 32 * 256; i += 1024) tile[i] = 0u;
  for (int i = t; i < kNB; i += 1024) cnt_s[i] = cnt[(b * 8 + band) * kNB + i];
  __syncthreads();

  const int w = t >> 6, lane = t & 63;
  const unsigned* segbase = xy_bkt + ((size_t)b * 8 + band) * kNB * kSlot;

  auto splat1 = [&](unsigned u) {
    int yf = (int)(u >> 16);
    int xf = (int)(u & 0xFFFFu);
    int ry = (yf >> 8) - r0;                 // -1..31 (straddle dups at -1)
    int x0 = xf >> 8;
    int fx = xf & 255, fy = yf & 255;
    int gx = 256 - fx, gy = 256 - fy;
    if ((unsigned)ry < 32u) {
      int base = ry * 256 + x0;
      atomicAdd(&tile[base],     (unsigned)((gx * gy + 2) >> 2));
      atomicAdd(&tile[base + 1], (unsigned)((fx * gy + 2) >> 2));
    }
    if ((unsigned)(ry + 1) < 32u) {
      int base = (ry + 1) * 256 + x0;
      atomicAdd(&tile[base],     (unsigned)((gx * fy + 2) >> 2));
      atomicAdd(&tile[base + 1], (unsigned)((fx * fy + 2) >> 2));
    }
  };

  for (int j = w; j < kNB; j += 16) {        // wave processes whole chunks
    int cc = cnt_s[j];
    if (lane < cc) splat1(segbase[(size_t)j * kSlot + lane]);
  }
  __syncthreads();

  // one wave per row-pair: rows 2w, 2w+1 packed as re+i*im
  const int rowA = 2 * w;
  constexpr float scale = 1.0f / 16384.0f;
  float2 v[4];
#pragma unroll
  for (int j = 0; j < 4; ++j) {
    int i = lane + 64 * j;
    v[j] = make_float2((float)tile[rowA * 256 + i] * scale,
                       (float)tile[(rowA + 1) * 256 + i] * scale);
  }
  fft256w<-1>(v, fbuf[w], lane, tw);
  float2* a = fbuf[w];                        // holds all 256 spectrum values
  const int y = r0 + rowA;
#pragma unroll
  for (int j = 0; j < 2; ++j) {
    int k = lane + 64 * j;
    float2 Zk = a[k], Zm = a[(256 - k) & 255];
    float4 o = make_float4(0.5f * (Zk.x + Zm.x), 0.5f * (Zk.y - Zm.y),
                           0.5f * (Zk.y + Zm.y), 0.5f * (Zm.x - Zk.x));
    *reinterpret_cast<float4*>(&FcT[((size_t)b * kKx + k) * kS + y]) = o;
  }
  if (lane == 0) {                            // Nyquist k=128
    float2 Zk = a[128];
    *reinterpret_cast<float4*>(&FcT[((size_t)b * kKx + 128) * kS + y]) =
        make_float4(Zk.x, 0.f, Zk.y, 0.f);
  }
}

// ---------------------------------------------------------------------------
// Column FFT * H * inverse column FFT; one wave per (pose, kx) column.
// grid: 32 poses * 33 blocks (4 cols/block); kx > 128 waves exit early.
// ---------------------------------------------------------------------------
__global__ __launch_bounds__(256) void k_fft_cols(float2* __restrict__ FcT,
                                                  const float* __restrict__ defocus) {
  __shared__ float2 fbuf[4][256];
  __shared__ float2 tw[128];
  const int t = threadIdx.x, w = t >> 6, lane = t & 63;
  build_tw(tw, t);
  const int b = blockIdx.x / 33;
  const int kx = (blockIdx.x % 33) * 4 + w;
  __syncthreads();                            // tw ready
  if (kx > 128) return;
  float2* col = FcT + ((size_t)b * kKx + kx) * kS;
  float2 v[4];
#pragma unroll
  for (int j = 0; j < 4; ++j) v[j] = col[lane + 64 * j];
  fft256w<-1>(v, fbuf[w], lane, tw);

  const float D = defocus[b];
  const float fxv = (float)kx * (1.0f / 256.0f);
  const float fx2 = fxv * fxv;
#pragma unroll
  for (int j = 0; j < 4; ++j) {
    int ky = lane + 64 * j;
    float fyv = (float)(ky < 128 ? ky : ky - 256) * (1.0f / 256.0f);
    float s2 = fyv * fyv + fx2;
    float G = __expf(-kGauss * s2);
    float chi = kA1 * D * s2 - kA2 * s2 * s2;
    float sn, cn;
    sincosf(chi, &sn, &cn);
    float H = G * (-(kW1 * sn + kQ0 * cn));
    v[j].x *= H;
    v[j].y *= H;
  }
  fft256w<1>(v, fbuf[w], lane, tw);
#pragma unroll
  for (int j = 0; j < 4; ++j) col[lane + 64 * j] = v[j];
}

// ---------------------------------------------------------------------------
// Inverse row FFT: one wave per row-pair (y=2p, 2p+1). Hermitian-extend the
// 129 stored kx into the full 256-pt spectrum per wave, then barrier-free
// inverse FFT; real parts -> two output rows. grid: 32 poses * 32 blocks.
// ---------------------------------------------------------------------------
__global__ __launch_bounds__(256) void k_fft_rows_inv(const float2* __restrict__ FcT,
                                                      float* __restrict__ out) {
  __shared__ float2 fbuf[4][256];
  __shared__ float4 smT[4][132];
  __shared__ float2 tw[128];
  const int t = threadIdx.x, w = t >> 6, lane = t & 63;
  build_tw(tw, t);
  const int b = blockIdx.x >> 5;
  const int pp = (blockIdx.x & 31) * 4 + w;   // pair 0..127
  const int y = 2 * pp;

  const float4* Fp = reinterpret_cast<const float4*>(FcT + (size_t)b * kKx * kS + y);
  const size_t kstep = kS / 2;                // float4s between consecutive k
  smT[w][lane]      = Fp[(size_t)lane * kstep];
  smT[w][lane + 64] = Fp[(size_t)(lane + 64) * kstep];
  if (lane == 0) smT[w][128] = Fp[(size_t)128 * kstep];
  __syncthreads();                            // tw ready (smT is per-wave)

  float2 v[4];
  {
    float4 f = smT[w][lane];
    v[0] = make_float2(f.x - f.w, f.y + f.z);
  }
  {
    float4 f = smT[w][lane + 64];
    v[1] = make_float2(f.x - f.w, f.y + f.z);
  }
  if (lane == 0) {
    float4 f = smT[w][128];
    v[2] = make_float2(f.x - f.w, f.y + f.z);
  } else {
    float4 f = smT[w][128 - lane];            // Hermitian: k=128+lane
    v[2] = make_float2(f.x + f.w, -f.y + f.z);
  }
  {
    float4 f = smT[w][64 - lane];             // Hermitian: k=192+lane
    v[3] = make_float2(f.x + f.w, -f.y + f.z);
  }
  fft256w<1>(v, fbuf[w], lane, tw);

  float* o0 = out + ((size_t)b * kS + y) * kS;
  float* o1 = o0 + kS;
#pragma unroll
  for (int j = 0; j < 4; ++j) {
    int i = lane + 64 * j;
    o0[i] = v[j].x * (1.0f / 65536.0f);
    o1[i] = v[j].y * (1.0f / 65536.0f);
  }
}

// ---------------------------------------------------------------------------
extern "C" void kernel_launch(void* const* d_in, const int* in_sizes, int n_in,
                              void* d_out, int out_size, void* d_ws, size_t ws_size,
                              hipStream_t stream) {
  const float* c_nma        = (const float*)d_in[0];
  const float* delta_euler  = (const float*)d_in[1];
  const float* delta_shifts = (const float*)d_in[2];
  const float* coords       = (const float*)d_in[3];
  const float* basis_x      = (const float*)d_in[4];
  const float* basis_y      = (const float*)d_in[5];
  const float* basis_z      = (const float*)d_in[6];
  const float* euler_base   = (const float*)d_in[7];
  const float* shifts_base  = (const float*)d_in[8];
  const float* defocus      = (const float*)d_in[9];

  float* out = (float*)d_out;
  float* decoded = out;                                   // B*S*S
  float* bond    = out + (size_t)kB * kS * kS;            // B*(N-1)
  float* angle   = bond + (size_t)kB * (kN - 1);          // B*(N-2)

  char* ws = (char*)d_ws;
  // xy_bkt: 32 poses * 8 bands * 404 blocks * 64 slots * 4B = 26.5 MB
  const size_t bktBytes = (size_t)kB * 8 * kNB * kSlot * sizeof(unsigned);
  unsigned* xy_bkt = (unsigned*)ws;
  int*      cnt    = (int*)(ws + bktBytes);                      // 413 KB
  float2*   FcT    = (float2*)(ws + (size_t)28 * 1024 * 1024);   // [28MB, 36.5MB)

  k_deform<<<kNB * 4, 256, 0, stream>>>(c_nma, delta_euler, delta_shifts, coords,
                                        basis_x, basis_y, basis_z, euler_base,
                                        shifts_base, xy_bkt, cnt, bond, angle);
  k_splat_fft<<<kB * 8, 1024, 0, stream>>>(xy_bkt, cnt, FcT);
  k_fft_cols<<<kB * 33, 256, 0, stream>>>(FcT, defocus);
  k_fft_rows_inv<<<kB * 32, 256, 0, stream>>>(FcT, decoded);
}

// Round 16
// 57.066 us; speedup vs baseline: 1.1803x; 1.1803x over previous
//
#include <hip/hip_runtime.h>
#include <math.h>

namespace {
constexpr int kB = 32;
constexpr int kN = 100000;
constexpr int kL = 12;
constexpr int kS = 256;
constexpr int kBG = 8;                      // poses per block in deform kernel
constexpr int kWOwn = 62;                   // atoms OWNED per wave (2 shuffle-halo lanes)
constexpr int kTile = 4 * kWOwn;            // 248 atoms owned per 256-thread block
constexpr int kNB = (kN + kTile - 1) / kTile;  // 404 atom-blocks
constexpr int kSlot = 64;                   // slots per (pose, band, source-block)
constexpr int kKx = 130;                    // stored kx columns (129 used + pad)

constexpr float kGauss = (float)(2.0 * M_PI * M_PI);                         // 2(pi*sigma)^2, sigma=1
constexpr float kA1 = (float)(M_PI * 0.0197);                                // pi*lambda
constexpr float kA2 = (float)(0.5 * M_PI * 2.7e7 * 0.0197 * 0.0197 * 0.0197);// 0.5*pi*Cs*lambda^3
constexpr float kW1 = 0.99498743710661995f;                                  // sqrt(1-Q0^2)
constexpr float kQ0 = 0.1f;
}

__device__ __forceinline__ void build_tw(float2* tw, int t) {
  if (t < 128) {
    float s, c;
    sincosf((float)M_PI / 128.0f * (float)t, &s, &c);
    tw[t] = make_float2(c, s);
  }
}

// ---------------------------------------------------------------------------
// PER-WAVE 256-point Stockham radix-4 FFT: 64 lanes, 4 float2 regs/lane,
// 4 stages (m = 1,4,16,64), single 256-float2 LDS work buffer, NO barriers.
// ---------------------------------------------------------------------------
template <int SIGN>
__device__ __forceinline__ void fft256w(float2 v[4], float2* fb, int lane,
                                        const float2* tw) {
#pragma unroll
  for (int m = 1; m <= 64; m *= 4) {
    int l = lane & (m - 1);
    int jm = lane - l;                 // u*m
    float2 wv = tw[jm];
    float c = wv.x;
    float s = (SIGN < 0) ? -wv.y : wv.y;
    float2 A0 = v[0], A1 = v[1], A2 = v[2], A3 = v[3];
    float s02x = A0.x + A2.x, s02y = A0.y + A2.y;
    float d02x = A0.x - A2.x, d02y = A0.y - A2.y;
    float s13x = A1.x + A3.x, s13y = A1.y + A3.y;
    float d13x = A1.x - A3.x, d13y = A1.y - A3.y;
    float jdx = (SIGN < 0) ? d13y : -d13y;      // sgn*i*(d13)
    float jdy = (SIGN < 0) ? -d13x : d13x;
    float t1x = d02x + jdx, t1y = d02y + jdy;
    float t2x = s02x - s13x, t2y = s02y - s13y;
    float t3x = d02x - jdx, t3y = d02y - jdy;
    float c2 = c * c - s * s, s2 = 2.f * c * s;
    float c3 = c2 * c - s2 * s, s3 = c2 * s + s2 * c;
    int ob = 4 * jm + l;
    fb[ob]         = make_float2(s02x + s13x, s02y + s13y);
    fb[ob + m]     = make_float2(c * t1x - s * t1y, c * t1y + s * t1x);
    fb[ob + 2 * m] = make_float2(c2 * t2x - s2 * t2y, c2 * t2y + s2 * t2x);
    fb[ob + 3 * m] = make_float2(c3 * t3x - s3 * t3y, c3 * t3y + s3 * t3x);
    v[0] = fb[lane];
    v[1] = fb[lane + 64];
    v[2] = fb[lane + 128];
    v[3] = fb[lane + 192];
  }
}

// ---------------------------------------------------------------------------
// Phase A: deformation -> bond, angle, projected (x,y) packed u16.8 scattered
// DIRECTLY into deterministic per-(pose, band, source-block) 64-slot chunks
// (rank from LDS atomic; no global reservation, no gcount, no second pass).
// Per-chunk counts written once at the end (single writer -> no zero-init).
// Straddle atoms (y0%32==31) duplicated into the next band's chunk.
// NOTE r15 lesson: xy_bkt scatter stores MUST stay L2-cached (plain stores)
// -- nontemporal scattered 4B stores cost ~200MB of HBM sector traffic and
// kill splat's L2 reuse (57->67us regression).
// ---------------------------------------------------------------------------
__global__ __launch_bounds__(256) void k_deform(
    const float* __restrict__ c_nma, const float* __restrict__ delta_euler,
    const float* __restrict__ delta_shifts, const float* __restrict__ coords,
    const float* __restrict__ basis_x, const float* __restrict__ basis_y,
    const float* __restrict__ basis_z, const float* __restrict__ euler_base,
    const float* __restrict__ shifts_base,
    unsigned* __restrict__ xy_bkt, int* __restrict__ cnt,
    float* __restrict__ bond, float* __restrict__ angle) {
  __shared__ float cn_s[kBG][kL];
  __shared__ float rsh_s[kBG][8];
  __shared__ int bcnt[kBG][8];

  const int t = threadIdx.x;
  const int wave = t >> 6, lane = t & 63;
  const int bg = blockIdx.y * kBG;
  const int xb = blockIdx.x;
  const int n = xb * kTile + wave * kWOwn + lane;
  const bool owner = (lane < kWOwn) && (n < kN);
  const int nc = min(n, kN - 1);

  if (t < kBG * kL) cn_s[t / kL][t % kL] = c_nma[(bg + t / kL) * kL + (t % kL)];
  if (t < kBG) {
    int b = bg + t;
    float rot  = euler_base[b * 3 + 0] + delta_euler[b * 3 + 0];
    float tilt = euler_base[b * 3 + 1] + delta_euler[b * 3 + 1];
    float psi  = euler_base[b * 3 + 2] + delta_euler[b * 3 + 2];
    float ca = cosf(rot), sa = sinf(rot);
    float cb = cosf(tilt), sb = sinf(tilt);
    float cg = cosf(psi), sg = sinf(psi);
    rsh_s[t][0] = cg * cb * ca - sg * sa;
    rsh_s[t][1] = cg * cb * sa + sg * ca;
    rsh_s[t][2] = -cg * sb;
    rsh_s[t][3] = -sg * cb * ca - cg * sa;
    rsh_s[t][4] = -sg * cb * sa + cg * ca;
    rsh_s[t][5] = sg * sb;
    rsh_s[t][6] = shifts_base[b * 2 + 0] + delta_shifts[b * 2 + 0] + 128.0f;
    rsh_s[t][7] = shifts_base[b * 2 + 1] + delta_shifts[b * 2 + 1] + 128.0f;
  }
  if (t < kBG * 8) bcnt[t >> 3][t & 7] = 0;

  const float cx = coords[nc * 3 + 0];
  const float cy = coords[nc * 3 + 1];
  const float cz = coords[nc * 3 + 2];
  float bx[kL], by[kL], bz[kL];
  {
    const float4* px4 = reinterpret_cast<const float4*>(basis_x + (size_t)nc * kL);
    const float4* py4 = reinterpret_cast<const float4*>(basis_y + (size_t)nc * kL);
    const float4* pz4 = reinterpret_cast<const float4*>(basis_z + (size_t)nc * kL);
#pragma unroll
    for (int q = 0; q < 3; ++q) {
      float4 vx = px4[q], vy = py4[q], vz = pz4[q];
      bx[q * 4 + 0] = vx.x; bx[q * 4 + 1] = vx.y; bx[q * 4 + 2] = vx.z; bx[q * 4 + 3] = vx.w;
      by[q * 4 + 0] = vy.x; by[q * 4 + 1] = vy.y; by[q * 4 + 2] = vy.z; by[q * 4 + 3] = vy.w;
      bz[q * 4 + 0] = vz.x; bz[q * 4 + 1] = vz.y; bz[q * 4 + 2] = vz.z; bz[q * 4 + 3] = vz.w;
    }
  }
  __syncthreads();

#pragma unroll
  for (int bi = 0; bi < kBG; ++bi) {
    const int b = bg + bi;
    float px = cx, py = cy, pz = cz;
#pragma unroll
    for (int l = 0; l < kL; ++l) {
      float cc = cn_s[bi][l];
      px = fmaf(cc, bx[l], px);
      py = fmaf(cc, by[l], py);
      pz = fmaf(cc, bz[l], pz);
    }
    float p1x = __shfl_down(px, 1), p1y = __shfl_down(py, 1), p1z = __shfl_down(pz, 1);
    float dx = p1x - px, dy = p1y - py, dz = p1z - pz;
    float dd = fmaf(dx, dx, fmaf(dy, dy, dz * dz));
    float d1x = __shfl_down(dx, 1), d1y = __shfl_down(dy, 1), d1z = __shfl_down(dz, 1);

    if (owner) {
      float xr = fmaf(rsh_s[bi][0], px, fmaf(rsh_s[bi][1], py, fmaf(rsh_s[bi][2], pz, rsh_s[bi][6])));
      float yr = fmaf(rsh_s[bi][3], px, fmaf(rsh_s[bi][4], py, fmaf(rsh_s[bi][5], pz, rsh_s[bi][7])));
      xr = fminf(fmaxf(xr, 0.0f), 254.999f);
      yr = fminf(fmaxf(yr, 0.0f), 254.999f);
      unsigned xf = (unsigned)(xr * 256.0f);   // <= 65279 -> x0 <= 254
      unsigned yf = (unsigned)(yr * 256.0f);
      unsigned u = (yf << 16) | xf;
      unsigned y0i = yf >> 8;                  // 0..254
      unsigned band = y0i >> 5;                // 0..7
      int rank = atomicAdd(&bcnt[bi][band], 1);
      if (rank < kSlot)
        xy_bkt[(((size_t)b * 8 + band) * kNB + xb) * kSlot + rank] = u;
      if ((y0i & 31u) == 31u) {                // footprint straddles band edge
        unsigned band1 = band + 1;             // y0i<=223 -> band1<=7
        int r2 = atomicAdd(&bcnt[bi][band1], 1);
        if (r2 < kSlot)
          xy_bkt[(((size_t)b * 8 + band1) * kNB + xb) * kSlot + r2] = u;
      }
      if (n < kN - 1) {
        __builtin_nontemporal_store(sqrtf(dd + 1e-12f),
                                    &bond[(size_t)b * (kN - 1) + n]);
      }
      if (n < kN - 2) {
        float vv = fmaf(d1x, d1x, fmaf(d1y, d1y, d1z * d1z));
        float uv = -fmaf(dx, d1x, fmaf(dy, d1y, dz * d1z));
        float cosang = uv * rsqrtf(dd * vv);
        cosang = fminf(fmaxf(cosang, -0.9999f), 0.9999f);
        float ax = fabsf(cosang);
        float rt = sqrtf(1.0f - ax);
        float pp = fmaf(fmaf(fmaf(-0.0187293f, ax, 0.0742610f), ax, -0.2121144f),
                        ax, 1.5707288f);
        float res = rt * pp;
        __builtin_nontemporal_store((cosang >= 0.f) ? res : (float)M_PI - res,
                                    &angle[(size_t)b * (kN - 2) + n]);
      }
    }
  }
  __syncthreads();
  if (t < kBG * 8) {
    int po = t >> 3, bandx = t & 7;
    cnt[((bg + po) * 8 + bandx) * kNB + xb] = min(bcnt[po][bandx], kSlot);
  }
}

// ---------------------------------------------------------------------------
// Phase B (FUSED): splat from per-(pose,band) chunked slot lists into a
// 32x256 u18.14 LDS tile + 16 per-wave packed real row-FFTs, writing the
// Hermitian-reduced transposed spectrum FcT[b][kx][y] directly.
// grid: 32 poses * 8 bands, 1024 threads. Slot loads are predicated on the
// chunk count (unfilled slots are never fetched).
// ---------------------------------------------------------------------------
__global__ __launch_bounds__(1024) void k_splat_fft(
    const unsigned* __restrict__ xy_bkt, const int* __restrict__ cnt,
    float2* __restrict__ FcT) {
  __shared__ unsigned tile[32 * 256];
  __shared__ float2 fbuf[16][256];
  __shared__ float2 tw[128];
  __shared__ int cnt_s[kNB];
  const int t = threadIdx.x;
  const int b = blockIdx.x >> 3;
  const int band = blockIdx.x & 7;
  const int r0 = band * 32;
  build_tw(tw, t);
  for (int i = t; i < 32 * 256; i += 1024) tile[i] = 0u;
  for (int i = t; i < kNB; i += 1024) cnt_s[i] = cnt[(b * 8 + band) * kNB + i];
  __syncthreads();

  const int w = t >> 6, lane = t & 63;
  const unsigned* segbase = xy_bkt + ((size_t)b * 8 + band) * kNB * kSlot;

  auto splat1 = [&](unsigned u) {
    int yf = (int)(u >> 16);
    int xf = (int)(u & 0xFFFFu);
    int ry = (yf >> 8) - r0;                 // -1..31 (straddle dups at -1)
    int x0 = xf >> 8;
    int fx = xf & 255, fy = yf & 255;
    int gx = 256 - fx, gy = 256 - fy;
    if ((unsigned)ry < 32u) {
      int base = ry * 256 + x0;
      atomicAdd(&tile[base],     (unsigned)((gx * gy + 2) >> 2));
      atomicAdd(&tile[base + 1], (unsigned)((fx * gy + 2) >> 2));
    }
    if ((unsigned)(ry + 1) < 32u) {
      int base = (ry + 1) * 256 + x0;
      atomicAdd(&tile[base],     (unsigned)((gx * fy + 2) >> 2));
      atomicAdd(&tile[base + 1], (unsigned)((fx * fy + 2) >> 2));
    }
  };

  for (int j = w; j < kNB; j += 16) {        // wave processes whole chunks
    int cc = cnt_s[j];
    if (lane < cc) splat1(segbase[(size_t)j * kSlot + lane]);
  }
  __syncthreads();

  // one wave per row-pair: rows 2w, 2w+1 packed as re+i*im
  const int rowA = 2 * w;
  constexpr float scale = 1.0f / 16384.0f;
  float2 v[4];
#pragma unroll
  for (int j = 0; j < 4; ++j) {
    int i = lane + 64 * j;
    v[j] = make_float2((float)tile[rowA * 256 + i] * scale,
                       (float)tile[(rowA + 1) * 256 + i] * scale);
  }
  fft256w<-1>(v, fbuf[w], lane, tw);
  float2* a = fbuf[w];                        // holds all 256 spectrum values
  const int y = r0 + rowA;
#pragma unroll
  for (int j = 0; j < 2; ++j) {
    int k = lane + 64 * j;
    float2 Zk = a[k], Zm = a[(256 - k) & 255];
    float4 o = make_float4(0.5f * (Zk.x + Zm.x), 0.5f * (Zk.y - Zm.y),
                           0.5f * (Zk.y + Zm.y), 0.5f * (Zm.x - Zk.x));
    *reinterpret_cast<float4*>(&FcT[((size_t)b * kKx + k) * kS + y]) = o;
  }
  if (lane == 0) {                            // Nyquist k=128
    float2 Zk = a[128];
    *reinterpret_cast<float4*>(&FcT[((size_t)b * kKx + 128) * kS + y]) =
        make_float4(Zk.x, 0.f, Zk.y, 0.f);
  }
}

// ---------------------------------------------------------------------------
// Column FFT * H * inverse column FFT; one wave per (pose, kx) column.
// grid: 32 poses * 33 blocks (4 cols/block); kx > 128 waves exit early.
// ---------------------------------------------------------------------------
__global__ __launch_bounds__(256) void k_fft_cols(float2* __restrict__ FcT,
                                                  const float* __restrict__ defocus) {
  __shared__ float2 fbuf[4][256];
  __shared__ float2 tw[128];
  const int t = threadIdx.x, w = t >> 6, lane = t & 63;
  build_tw(tw, t);
  const int b = blockIdx.x / 33;
  const int kx = (blockIdx.x % 33) * 4 + w;
  __syncthreads();                            // tw ready
  if (kx > 128) return;
  float2* col = FcT + ((size_t)b * kKx + kx) * kS;
  float2 v[4];
#pragma unroll
  for (int j = 0; j < 4; ++j) v[j] = col[lane + 64 * j];
  fft256w<-1>(v, fbuf[w], lane, tw);

  const float D = defocus[b];
  const float fxv = (float)kx * (1.0f / 256.0f);
  const float fx2 = fxv * fxv;
#pragma unroll
  for (int j = 0; j < 4; ++j) {
    int ky = lane + 64 * j;
    float fyv = (float)(ky < 128 ? ky : ky - 256) * (1.0f / 256.0f);
    float s2 = fyv * fyv + fx2;
    float G = __expf(-kGauss * s2);
    float chi = kA1 * D * s2 - kA2 * s2 * s2;
    float sn, cn;
    sincosf(chi, &sn, &cn);
    float H = G * (-(kW1 * sn + kQ0 * cn));
    v[j].x *= H;
    v[j].y *= H;
  }
  fft256w<1>(v, fbuf[w], lane, tw);
#pragma unroll
  for (int j = 0; j < 4; ++j) col[lane + 64 * j] = v[j];
}

// ---------------------------------------------------------------------------
// Inverse row FFT: one wave per row-pair (y=2p, 2p+1). Hermitian-extend the
// 129 stored kx into the full 256-pt spectrum per wave, then barrier-free
// inverse FFT; real parts -> two output rows. grid: 32 poses * 32 blocks.
// ---------------------------------------------------------------------------
__global__ __launch_bounds__(256) void k_fft_rows_inv(const float2* __restrict__ FcT,
                                                      float* __restrict__ out) {
  __shared__ float2 fbuf[4][256];
  __shared__ float4 smT[4][132];
  __shared__ float2 tw[128];
  const int t = threadIdx.x, w = t >> 6, lane = t & 63;
  build_tw(tw, t);
  const int b = blockIdx.x >> 5;
  const int pp = (blockIdx.x & 31) * 4 + w;   // pair 0..127
  const int y = 2 * pp;

  const float4* Fp = reinterpret_cast<const float4*>(FcT + (size_t)b * kKx * kS + y);
  const size_t kstep = kS / 2;                // float4s between consecutive k
  smT[w][lane]      = Fp[(size_t)lane * kstep];
  smT[w][lane + 64] = Fp[(size_t)(lane + 64) * kstep];
  if (lane == 0) smT[w][128] = Fp[(size_t)128 * kstep];
  __syncthreads();                            // tw ready (smT is per-wave)

  float2 v[4];
  {
    float4 f = smT[w][lane];
    v[0] = make_float2(f.x - f.w, f.y + f.z);
  }
  {
    float4 f = smT[w][lane + 64];
    v[1] = make_float2(f.x - f.w, f.y + f.z);
  }
  if (lane == 0) {
    float4 f = smT[w][128];
    v[2] = make_float2(f.x - f.w, f.y + f.z);
  } else {
    float4 f = smT[w][128 - lane];            // Hermitian: k=128+lane
    v[2] = make_float2(f.x + f.w, -f.y + f.z);
  }
  {
    float4 f = smT[w][64 - lane];             // Hermitian: k=192+lane
    v[3] = make_float2(f.x + f.w, -f.y + f.z);
  }
  fft256w<1>(v, fbuf[w], lane, tw);

  float* o0 = out + ((size_t)b * kS + y) * kS;
  float* o1 = o0 + kS;
#pragma unroll
  for (int j = 0; j < 4; ++j) {
    int i = lane + 64 * j;
    o0[i] = v[j].x * (1.0f / 65536.0f);
    o1[i] = v[j].y * (1.0f / 65536.0f);
  }
}

// ---------------------------------------------------------------------------
extern "C" void kernel_launch(void* const* d_in, const int* in_sizes, int n_in,
                              void* d_out, int out_size, void* d_ws, size_t ws_size,
                              hipStream_t stream) {
  const float* c_nma        = (const float*)d_in[0];
  const float* delta_euler  = (const float*)d_in[1];
  const float* delta_shifts = (const float*)d_in[2];
  const float* coords       = (const float*)d_in[3];
  const float* basis_x      = (const float*)d_in[4];
  const float* basis_y      = (const float*)d_in[5];
  const float* basis_z      = (const float*)d_in[6];
  const float* euler_base   = (const float*)d_in[7];
  const float* shifts_base  = (const float*)d_in[8];
  const float* defocus      = (const float*)d_in[9];

  float* out = (float*)d_out;
  float* decoded = out;                                   // B*S*S
  float* bond    = out + (size_t)kB * kS * kS;            // B*(N-1)
  float* angle   = bond + (size_t)kB * (kN - 1);          // B*(N-2)

  char* ws = (char*)d_ws;
  // xy_bkt: 32 poses * 8 bands * 404 blocks * 64 slots * 4B = 26.5 MB
  const size_t bktBytes = (size_t)kB * 8 * kNB * kSlot * sizeof(unsigned);
  unsigned* xy_bkt = (unsigned*)ws;
  int*      cnt    = (int*)(ws + bktBytes);                      // 413 KB
  float2*   FcT    = (float2*)(ws + (size_t)28 * 1024 * 1024);   // [28MB, 36.5MB)

  dim3 gd(kNB, kB / kBG);
  k_deform<<<gd, 256, 0, stream>>>(c_nma, delta_euler, delta_shifts, coords,
                                   basis_x, basis_y, basis_z, euler_base,
                                   shifts_base, xy_bkt, cnt, bond, angle);
  k_splat_fft<<<kB * 8, 1024, 0, stream>>>(xy_bkt, cnt, FcT);
  k_fft_cols<<<kB * 33, 256, 0, stream>>>(FcT, defocus);
  k_fft_rows_inv<<<kB * 32, 256, 0, stream>>>(FcT, decoded);
}